// Round 3
// baseline (1038.920 us; speedup 1.0000x reference)
//
#include <hip/hip_runtime.h>
#include <hip/hip_bf16.h>
#include <stdint.h>

// TreeLSTM on MI355X (gfx950) — fully fused subtree kernel.
// Each block owns 8 level-3 roots => 128 leaves. All h/c state lives in LDS;
// logits for every node are emitted directly. d_ws holds only idempotently
// packed bf16 weights (0.5 MiB), so the kernel is replay/poison-proof.

#define THREADS 256

typedef __attribute__((ext_vector_type(8))) short short8;
typedef __attribute__((ext_vector_type(4))) float f32x4;

__device__ __forceinline__ unsigned short f2bf(float x) {
    unsigned u = __float_as_uint(x);
    u += 0x7fffu + ((u >> 16) & 1u);   // round-to-nearest-even
    return (unsigned short)(u >> 16);
}
__device__ __forceinline__ float bf2f(unsigned short b) {
    return __uint_as_float(((unsigned)b) << 16);
}
__device__ __forceinline__ float sigm(float x) { return 1.0f / (1.0f + __expf(-x)); }

// ---------------------------------------------------------------------------
// Pack W_iou (384x256) -> Wl ; [U_iou (384x256); U_f (256x256)] -> Wc (640x256)
__global__ __launch_bounds__(256)
void prep_kernel(const float* __restrict__ W_iou,
                 const float* __restrict__ U_iou,
                 const float* __restrict__ U_f,
                 unsigned short* __restrict__ Wl,
                 unsigned short* __restrict__ Wc)
{
    const int i = blockIdx.x * 256 + threadIdx.x;   // grid covers 98304
    if (i < 98304) {
        Wl[i] = f2bf(W_iou[i]);
        Wc[i] = f2bf(U_iou[i]);
    }
    if (i < 65536) {
        Wc[98304 + i] = f2bf(U_f[i]);
    }
}

// ---------------------------------------------------------------------------
// One level's GEMM + LSTM epilogue.
// B-tile rows (512B each, XOR-16B-chunk swizzled): row j = [h_prev[2j]|h_prev[2j+1]]
// (for leaves: row i = emb[tok[i]]). Swapped MFMA: D[n][node]; wave w owns
// p-slices {2w,2w+1}; col groups n = p + j*128 keep i,o,u,f0,f1 in one lane.
template<int NCOL, int G, bool WC>
__device__ __forceinline__ void level_step(
    const unsigned short* __restrict__ Wg,     // [NCOL*128][256] bf16, global
    const unsigned char* Blds,                 // B-tile base in LDS
    unsigned char* h_out,                      // LDS, B-tile format for next level
    unsigned short* c_out,                     // LDS, col-major [p][nslot_out]
    const unsigned short* c_prev, int nslot_prev,
    const float* __restrict__ b_iou, const float* __restrict__ b_f,
    int w, int lrow, int lk, int slotBase, int nslot_out, int mvalid)
{
    f32x4 acc[2][NCOL][G];
    #pragma unroll
    for (int u = 0; u < 2; ++u)
        #pragma unroll
        for (int j = 0; j < NCOL; ++j)
            #pragma unroll
            for (int g = 0; g < G; ++g)
                acc[u][j][g] = (f32x4){0.f, 0.f, 0.f, 0.f};

    #pragma unroll
    for (int ks = 0; ks < 8; ++ks) {
        short8 aW[2][NCOL];
        #pragma unroll
        for (int u = 0; u < 2; ++u)
            #pragma unroll
            for (int j = 0; j < NCOL; ++j) {
                const int n = (2 * w + u) * 16 + lrow + j * 128;
                aW[u][j] = *reinterpret_cast<const short8*>(
                    Wg + (size_t)n * 256 + ks * 32 + lk * 8);
            }
        #pragma unroll
        for (int g = 0; g < G; ++g) {
            const int row = g * 16 + lrow;
            const int chunk = (ks * 4 + lk) ^ (row & 7);
            short8 bN = *reinterpret_cast<const short8*>(
                Blds + row * 512 + (chunk << 4));
            #pragma unroll
            for (int u = 0; u < 2; ++u)
                #pragma unroll
                for (int j = 0; j < NCOL; ++j)
                    acc[u][j][g] = __builtin_amdgcn_mfma_f32_16x16x32_bf16(
                        aW[u][j], bN, acc[u][j][g], 0, 0, 0);
        }
    }

    #pragma unroll
    for (int g = 0; g < G; ++g) {
        const int ml = slotBase + g * 16 + lrow;   // local slot at this level
        if (ml < mvalid) {
            #pragma unroll
            for (int u = 0; u < 2; ++u) {
                #pragma unroll
                for (int r = 0; r < 4; ++r) {
                    const int p = (2 * w + u) * 16 + lk * 4 + r;
                    float iv = acc[u][0][g][r] + b_iou[p];
                    float ov = acc[u][1][g][r] + b_iou[128 + p];
                    float uv = acc[u][2][g][r] + b_iou[256 + p];
                    float csum = 0.f;
                    if (NCOL == 5) {
                        float f0 = acc[u][3][g][r] + b_f[p];
                        float f1 = acc[u][4][g][r] + b_f[128 + p];
                        csum = sigm(f0) * bf2f(c_prev[p * nslot_prev + 2 * ml])
                             + sigm(f1) * bf2f(c_prev[p * nslot_prev + 2 * ml + 1]);
                    }
                    float cv = sigm(iv) * tanhf(uv) + csum;
                    float hv = sigm(ov) * tanhf(cv);
                    if (WC) c_out[p * nslot_out + ml] = f2bf(cv);
                    const int jr = ml >> 1;
                    const int q = (ml & 1) * 16 + (p >> 3);
                    *reinterpret_cast<unsigned short*>(
                        h_out + jr * 512 + ((q ^ (jr & 7)) << 4) + (p & 7) * 2)
                        = f2bf(hv);
                }
            }
        }
    }
}

// logits for M local nodes from swizzled LDS h; 4 lanes per node.
__device__ __forceinline__ void logits_emit(
    const unsigned char* h_lds, int M, const int* idsLds, int idBase,
    int segOff, const float* __restrict__ W_lin, const float* __restrict__ b_lin,
    float* __restrict__ out, int t)
{
    const int s = t >> 2, sub = t & 3;
    if (s >= M) return;
    float hv[32];
    const int j = s >> 1;
    #pragma unroll
    for (int qq = 0; qq < 4; ++qq) {
        const int q = (s & 1) * 16 + sub * 4 + qq;
        short8 v = *reinterpret_cast<const short8*>(
            h_lds + j * 512 + ((q ^ (j & 7)) << 4));
        #pragma unroll
        for (int e = 0; e < 8; ++e) hv[qq * 8 + e] = bf2f((unsigned short)v[e]);
    }
    const int gid = idsLds ? idsLds[s] : (idBase + s);
    float dots[5];
    #pragma unroll
    for (int cl = 0; cl < 5; ++cl) {
        const float* wr = W_lin + cl * 128 + sub * 32;
        float d = 0.f;
        #pragma unroll
        for (int k = 0; k < 32; ++k) d += hv[k] * wr[k];
        d += __shfl_xor(d, 1);
        d += __shfl_xor(d, 2);
        dots[cl] = d;
    }
    if (sub == 0) {
        #pragma unroll
        for (int cl = 0; cl < 5; ++cl)
            out[(size_t)(segOff + gid) * 5 + cl] = dots[cl] + b_lin[cl];
    }
}

// ---------------------------------------------------------------------------
__global__ __launch_bounds__(THREADS)
void tree_kernel(const int*  __restrict__ leaf_x,
                 const int2* __restrict__ cpairs,   // l1:[0,131072) l2:+131072 l3:+196608
                 const float* __restrict__ emb,
                 const unsigned short* __restrict__ Wl,
                 const unsigned short* __restrict__ Wc,
                 const float* __restrict__ b_iou,
                 const float* __restrict__ b_f,
                 const float* __restrict__ W_lin,
                 const float* __restrict__ b_lin,
                 float* __restrict__ out)
{
    // Arena (49152 B):
    //   X0 [0,16K)       leaf B half-tile (32 rows x 512B)
    //   h0 [16K,32K)     32 rows        c0 [32K,48K)  [p][64] bf16
    //   h1 [0,8K)        16 rows (reuses X0 after leaves done)
    //   c1 [8K,16K)      [p][32]
    //   h2 [16K,24K)     8 real rows (+8 stale, outputs discarded)
    //   c2 [24K,28K)     [p][16]
    //   h3 [28K,30K)     4 rows
    __shared__ unsigned char arena[49152];
    __shared__ int ids0[64], ids1[32], ids2[16], tok[64];

    const int t    = threadIdx.x;
    const int lane = t & 63;
    const int w    = t >> 6;
    const int lrow = lane & 15;
    const int lk   = lane >> 4;
    const int blk3 = blockIdx.x * 8;   // 8 level-3 roots per block

    // ---- id chase: local slot s's children are local slots 2s,2s+1 ----
    if (t < 8)  { int2 p = cpairs[196608 + blk3 + t]; ids2[2*t] = p.x; ids2[2*t+1] = p.y; }
    __syncthreads();
    if (t < 16) { int2 p = cpairs[131072 + ids2[t]];  ids1[2*t] = p.x; ids1[2*t+1] = p.y; }
    __syncthreads();
    if (t < 32) { int2 p = cpairs[ids1[t]];           ids0[2*t] = p.x; ids0[2*t+1] = p.y; }
    __syncthreads();
    if (t < 64) { tok[t] = leaf_x[ids0[t]]; }
    __syncthreads();

    unsigned char*  X0 = arena;
    unsigned char*  h0 = arena + 16384;
    unsigned short* c0 = (unsigned short*)(arena + 32768);
    unsigned char*  h1 = arena;
    unsigned short* c1 = (unsigned short*)(arena + 8192);
    unsigned char*  h2 = arena + 16384;
    unsigned short* c2 = (unsigned short*)(arena + 24576);
    unsigned char*  h3 = arena + 28672;

    // ---- leaves: 64 nodes in two 32-row halves ----
    for (int half = 0; half < 2; ++half) {
        {
            const int c  = t & 31;      // 16B chunk
            const int r0 = t >> 5;      // [0,8)
            #pragma unroll
            for (int rr = 0; rr < 4; ++rr) {
                const int r  = r0 + rr * 8;            // [0,32)
                const int gi = tok[half * 32 + r];
                const float4* src = reinterpret_cast<const float4*>(
                    emb + (size_t)gi * 256 + c * 8);
                float4 a = src[0], b = src[1];
                short8 v;
                v[0]=(short)f2bf(a.x); v[1]=(short)f2bf(a.y);
                v[2]=(short)f2bf(a.z); v[3]=(short)f2bf(a.w);
                v[4]=(short)f2bf(b.x); v[5]=(short)f2bf(b.y);
                v[6]=(short)f2bf(b.z); v[7]=(short)f2bf(b.w);
                *reinterpret_cast<short8*>(X0 + r * 512 + ((c ^ (r & 7)) << 4)) = v;
            }
        }
        __syncthreads();
        level_step<3, 2, true>(Wl, X0, h0, c0, nullptr, 0, b_iou, b_f,
                               w, lrow, lk, half * 32, 64, 64);
        __syncthreads();
    }

    // ---- level 1: 32 nodes ----
    logits_emit(h0, 64, ids0, 0, 0, W_lin, b_lin, out, t);
    level_step<5, 2, true>(Wc, h0, h1, c1, c0, 64, b_iou, b_f,
                           w, lrow, lk, 0, 32, 32);
    __syncthreads();

    // ---- level 2: 16 nodes ----
    logits_emit(h1, 32, ids1, 0, 262144, W_lin, b_lin, out, t);
    level_step<5, 1, true>(Wc, h1, h2, c2, c1, 32, b_iou, b_f,
                           w, lrow, lk, 0, 16, 16);
    __syncthreads();

    // ---- level 3: 8 nodes (m-group padded to 16; stale B rows' outputs masked)
    logits_emit(h2, 16, ids2, 0, 393216, W_lin, b_lin, out, t);
    level_step<5, 1, false>(Wc, h2, h3, nullptr, c2, 16, b_iou, b_f,
                            w, lrow, lk, 0, 8, 8);
    __syncthreads();

    logits_emit(h3, 8, nullptr, blk3, 458752, W_lin, b_lin, out, t);
}

// ---------------------------------------------------------------------------
extern "C" void kernel_launch(void* const* d_in, const int* in_sizes, int n_in,
                              void* d_out, int out_size, void* d_ws, size_t ws_size,
                              hipStream_t stream)
{
    const int*   leaf_x = (const int*)d_in[0];
    const int*   child  = (const int*)d_in[1];
    const float* emb    = (const float*)d_in[2];
    const float* W_iou  = (const float*)d_in[3];
    const float* U_iou  = (const float*)d_in[4];
    const float* b_iou  = (const float*)d_in[5];
    const float* U_f    = (const float*)d_in[6];
    const float* b_f    = (const float*)d_in[7];
    const float* W_lin  = (const float*)d_in[8];
    const float* b_lin  = (const float*)d_in[9];
    float* out = (float*)d_out;

    char* ws = (char*)d_ws;
    unsigned short* Wl = (unsigned short*)ws;                 // 192 KiB
    unsigned short* Wc = (unsigned short*)(ws + 196608);      // 320 KiB

    prep_kernel<<<384, 256, 0, stream>>>(W_iou, U_iou, U_f, Wl, Wc);

    tree_kernel<<<4096, THREADS, 0, stream>>>(
        leaf_x, (const int2*)child, emb, Wl, Wc,
        b_iou, b_f, W_lin, b_lin, out);
}

// Round 4
// 823.572 us; speedup vs baseline: 1.2615x; 1.2615x over previous
//
#include <hip/hip_runtime.h>
#include <hip/hip_bf16.h>
#include <stdint.h>

// TreeLSTM on MI355X (gfx950) — fully fused subtree kernel, v2.
// Each block owns 8 level-3 roots => 64 leaves. All h/c state lives in LDS;
// logits for every node are emitted directly. d_ws holds only idempotently
// packed bf16 weights (0.5 MiB), so the kernel is replay/poison-proof.
// v2: 8 waves/block, 1 p-slice per wave, single-shot leaf tile, VGPR<=128
// => 2 blocks/CU (16 resident waves) for latency hiding.

#define THREADS 512

typedef __attribute__((ext_vector_type(8))) short short8;
typedef __attribute__((ext_vector_type(4))) float f32x4;

__device__ __forceinline__ unsigned short f2bf(float x) {
    unsigned u = __float_as_uint(x);
    u += 0x7fffu + ((u >> 16) & 1u);   // round-to-nearest-even
    return (unsigned short)(u >> 16);
}
__device__ __forceinline__ float bf2f(unsigned short b) {
    return __uint_as_float(((unsigned)b) << 16);
}
__device__ __forceinline__ float sigm(float x) { return 1.0f / (1.0f + __expf(-x)); }

// ---------------------------------------------------------------------------
// Pack W_iou (384x256) -> Wl ; [U_iou (384x256); U_f (256x256)] -> Wc (640x256)
__global__ __launch_bounds__(256)
void prep_kernel(const float* __restrict__ W_iou,
                 const float* __restrict__ U_iou,
                 const float* __restrict__ U_f,
                 unsigned short* __restrict__ Wl,
                 unsigned short* __restrict__ Wc)
{
    const int i = blockIdx.x * 256 + threadIdx.x;   // grid covers 98304
    if (i < 98304) {
        Wl[i] = f2bf(W_iou[i]);
        Wc[i] = f2bf(U_iou[i]);
    }
    if (i < 65536) {
        Wc[98304 + i] = f2bf(U_f[i]);
    }
}

// ---------------------------------------------------------------------------
// One level's GEMM + LSTM epilogue.
// B-tile rows (512B, XOR-16B-chunk swizzled): row j = [h_prev[2j]|h_prev[2j+1]]
// (leaves: row i = emb[tok[i]]). Swapped MFMA: D[n][node]; wave w owns the
// p-slice [16w,16w+16); col groups n = p + j*128 keep i,o,u,f0,f1 in one lane.
template<int NCOL, int G, bool WC>
__device__ __forceinline__ void level_step(
    const unsigned short* __restrict__ Wg,     // [NCOL*128][256] bf16, global
    const unsigned char* Blds,                 // B-tile base in LDS
    unsigned char* h_out,                      // LDS, B-tile format for next level
    unsigned short* c_out,                     // LDS, col-major [p][nslot_out]
    const unsigned short* c_prev, int nslot_prev,
    const float* __restrict__ b_iou, const float* __restrict__ b_f,
    int w, int lrow, int lk, int nslot_out, int mvalid)
{
    const int q0 = w * 16;
    f32x4 acc[NCOL][G];
    #pragma unroll
    for (int j = 0; j < NCOL; ++j)
        #pragma unroll
        for (int g = 0; g < G; ++g)
            acc[j][g] = (f32x4){0.f, 0.f, 0.f, 0.f};

    #pragma unroll
    for (int ks = 0; ks < 8; ++ks) {
        short8 aW[NCOL];
        #pragma unroll
        for (int j = 0; j < NCOL; ++j) {
            const int n = q0 + lrow + j * 128;
            aW[j] = *reinterpret_cast<const short8*>(
                Wg + (size_t)n * 256 + ks * 32 + lk * 8);
        }
        #pragma unroll
        for (int g = 0; g < G; ++g) {
            const int row = g * 16 + lrow;          // B-tile row = node slot
            const int chunk = (ks * 4 + lk) ^ (row & 7);
            short8 bN = *reinterpret_cast<const short8*>(
                Blds + row * 512 + (chunk << 4));
            #pragma unroll
            for (int j = 0; j < NCOL; ++j)
                acc[j][g] = __builtin_amdgcn_mfma_f32_16x16x32_bf16(
                    aW[j], bN, acc[j][g], 0, 0, 0);
        }
    }

    #pragma unroll
    for (int g = 0; g < G; ++g) {
        const int ml = g * 16 + lrow;               // local node slot
        if (ml < mvalid) {
            #pragma unroll
            for (int r = 0; r < 4; ++r) {
                const int p = q0 + lk * 4 + r;
                float iv = acc[0][g][r] + b_iou[p];
                float ov = acc[1][g][r] + b_iou[128 + p];
                float uv = acc[2][g][r] + b_iou[256 + p];
                float csum = 0.f;
                if (NCOL == 5) {
                    float f0 = acc[3][g][r] + b_f[p];
                    float f1 = acc[4][g][r] + b_f[128 + p];
                    csum = sigm(f0) * bf2f(c_prev[p * nslot_prev + 2 * ml])
                         + sigm(f1) * bf2f(c_prev[p * nslot_prev + 2 * ml + 1]);
                }
                float cv = sigm(iv) * tanhf(uv) + csum;
                float hv = sigm(ov) * tanhf(cv);
                if (WC) c_out[p * nslot_out + ml] = f2bf(cv);
                const int jr = ml >> 1;
                const int q = (ml & 1) * 16 + (p >> 3);
                *reinterpret_cast<unsigned short*>(
                    h_out + jr * 512 + ((q ^ (jr & 7)) << 4) + (p & 7) * 2)
                    = f2bf(hv);
            }
        }
    }
}

// logits for M local nodes from swizzled LDS h; 4 lanes per node.
__device__ __forceinline__ void logits_emit(
    const unsigned char* h_lds, int M, const int* idsLds, int idBase,
    int segOff, const float* __restrict__ W_lin, const float* __restrict__ b_lin,
    float* __restrict__ out, int t)
{
    const int s = t >> 2, sub = t & 3;
    if (s >= M) return;
    float hv[32];
    const int j = s >> 1;
    #pragma unroll
    for (int qq = 0; qq < 4; ++qq) {
        const int q = (s & 1) * 16 + sub * 4 + qq;
        short8 v = *reinterpret_cast<const short8*>(
            h_lds + j * 512 + ((q ^ (j & 7)) << 4));
        #pragma unroll
        for (int e = 0; e < 8; ++e) hv[qq * 8 + e] = bf2f((unsigned short)v[e]);
    }
    const int gid = idsLds ? idsLds[s] : (idBase + s);
    float dots[5];
    #pragma unroll
    for (int cl = 0; cl < 5; ++cl) {
        const float* wr = W_lin + cl * 128 + sub * 32;
        float d = 0.f;
        #pragma unroll
        for (int k = 0; k < 32; ++k) d += hv[k] * wr[k];
        d += __shfl_xor(d, 1);
        d += __shfl_xor(d, 2);
        dots[cl] = d;
    }
    if (sub == 0) {
        #pragma unroll
        for (int cl = 0; cl < 5; ++cl)
            out[(size_t)(segOff + gid) * 5 + cl] = dots[cl] + b_lin[cl];
    }
}

// ---------------------------------------------------------------------------
__global__ __launch_bounds__(THREADS, 4)   // 4 waves/EU -> 2 blocks/CU, VGPR<=128
void tree_kernel(const int*  __restrict__ leaf_x,
                 const int2* __restrict__ cpairs,   // l1:[0,131072) l2:+131072 l3:+196608
                 const float* __restrict__ emb,
                 const unsigned short* __restrict__ Wl,
                 const unsigned short* __restrict__ Wc,
                 const float* __restrict__ b_iou,
                 const float* __restrict__ b_f,
                 const float* __restrict__ W_lin,
                 const float* __restrict__ b_lin,
                 float* __restrict__ out)
{
    // Arena (65536 B), region-overlaid:
    //   A [0,32768):      X0 leaf B-tile (64 rows x 512B)
    //                     -> h1 [0,8192) + c1 [8192,16384) + h3 [16384,18432)
    //   B [32768,49152):  h0 (32 rows) -> h2 [32768,36864) + c2 [36864,40960)
    //   C [49152,65536):  c0 [p][64] bf16
    __shared__ unsigned char arena[65536];
    __shared__ int ids0[64], ids1[32], ids2[16], tok[64];

    const int t    = threadIdx.x;
    const int lane = t & 63;
    const int w    = t >> 6;       // wave = p-slice, 8 waves
    const int lrow = lane & 15;
    const int lk   = lane >> 4;
    const int blk3 = blockIdx.x * 8;   // 8 level-3 roots per block

    // ---- id chase: local slot s's children are local slots 2s,2s+1 ----
    if (t < 8)  { int2 p = cpairs[196608 + blk3 + t]; ids2[2*t] = p.x; ids2[2*t+1] = p.y; }
    __syncthreads();
    if (t < 16) { int2 p = cpairs[131072 + ids2[t]];  ids1[2*t] = p.x; ids1[2*t+1] = p.y; }
    __syncthreads();
    if (t < 32) { int2 p = cpairs[ids1[t]];           ids0[2*t] = p.x; ids0[2*t+1] = p.y; }
    __syncthreads();
    if (t < 64) { tok[t] = leaf_x[ids0[t]]; }
    __syncthreads();

    unsigned char*  X0 = arena;
    unsigned char*  h0 = arena + 32768;
    unsigned short* c0 = (unsigned short*)(arena + 49152);
    unsigned char*  h1 = arena;
    unsigned short* c1 = (unsigned short*)(arena + 8192);
    unsigned char*  h2 = arena + 32768;
    unsigned short* c2 = (unsigned short*)(arena + 36864);
    unsigned char*  h3 = arena + 16384;

    // ---- stage 64 leaf rows (emb f32 -> bf16, XOR-swizzled 16B chunks) ----
    {
        const int c  = t & 31;      // 16B chunk
        const int r0 = t >> 5;      // [0,16)
        #pragma unroll
        for (int rr = 0; rr < 4; ++rr) {
            const int r  = r0 + rr * 16;           // [0,64)
            const int gi = tok[r];
            const float4* src = reinterpret_cast<const float4*>(
                emb + (size_t)gi * 256 + c * 8);
            float4 a = src[0], b = src[1];
            short8 v;
            v[0]=(short)f2bf(a.x); v[1]=(short)f2bf(a.y);
            v[2]=(short)f2bf(a.z); v[3]=(short)f2bf(a.w);
            v[4]=(short)f2bf(b.x); v[5]=(short)f2bf(b.y);
            v[6]=(short)f2bf(b.z); v[7]=(short)f2bf(b.w);
            *reinterpret_cast<short8*>(X0 + r * 512 + ((c ^ (r & 7)) << 4)) = v;
        }
    }
    __syncthreads();

    // ---- leaves: 64 nodes, one step (G=4) ----
    level_step<3, 4, true>(Wl, X0, h0, c0, nullptr, 0, b_iou, b_f,
                           w, lrow, lk, 64, 64);
    __syncthreads();

    // ---- level 1: 32 nodes ----
    logits_emit(h0, 64, ids0, 0, 0, W_lin, b_lin, out, t);
    level_step<5, 2, true>(Wc, h0, h1, c1, c0, 64, b_iou, b_f,
                           w, lrow, lk, 32, 32);
    __syncthreads();

    // ---- level 2: 16 nodes ----
    logits_emit(h1, 32, ids1, 0, 262144, W_lin, b_lin, out, t);
    level_step<5, 1, true>(Wc, h1, h2, c2, c1, 32, b_iou, b_f,
                           w, lrow, lk, 16, 16);
    __syncthreads();

    // ---- level 3: 8 nodes (m-group padded to 16; stale columns discarded) ----
    logits_emit(h2, 16, ids2, 0, 393216, W_lin, b_lin, out, t);
    level_step<5, 1, false>(Wc, h2, h3, nullptr, c2, 16, b_iou, b_f,
                            w, lrow, lk, 8, 8);
    __syncthreads();

    logits_emit(h3, 8, nullptr, blk3, 458752, W_lin, b_lin, out, t);
}

// ---------------------------------------------------------------------------
extern "C" void kernel_launch(void* const* d_in, const int* in_sizes, int n_in,
                              void* d_out, int out_size, void* d_ws, size_t ws_size,
                              hipStream_t stream)
{
    const int*   leaf_x = (const int*)d_in[0];
    const int*   child  = (const int*)d_in[1];
    const float* emb    = (const float*)d_in[2];
    const float* W_iou  = (const float*)d_in[3];
    const float* U_iou  = (const float*)d_in[4];
    const float* b_iou  = (const float*)d_in[5];
    const float* U_f    = (const float*)d_in[6];
    const float* b_f    = (const float*)d_in[7];
    const float* W_lin  = (const float*)d_in[8];
    const float* b_lin  = (const float*)d_in[9];
    float* out = (float*)d_out;

    char* ws = (char*)d_ws;
    unsigned short* Wl = (unsigned short*)ws;                 // 192 KiB
    unsigned short* Wc = (unsigned short*)(ws + 196608);      // 320 KiB

    prep_kernel<<<384, 256, 0, stream>>>(W_iou, U_iou, U_f, Wl, Wc);

    tree_kernel<<<4096, THREADS, 0, stream>>>(
        leaf_x, (const int2*)child, emb, Wl, Wc,
        b_iou, b_f, W_lin, b_lin, out);
}

// Round 6
// 808.660 us; speedup vs baseline: 1.2847x; 1.0184x over previous
//
#include <hip/hip_runtime.h>
#include <hip/hip_bf16.h>
#include <stdint.h>

// TreeLSTM on MI355X (gfx950) — fully fused subtree kernel, v3 (resubmit;
// round-5 bench was lost to an unresponsive container, not a kernel failure).
// Each block owns 8 level-3 roots => 64 leaves. All h/c state lives in LDS;
// logits for every node are emitted directly. d_ws holds only idempotently
// packed bf16 weights (0.5 MiB), so the kernel is replay/poison-proof.
// v3: explicit 2-deep W double-buffer (hide L2 latency), packed logits stores
// (kill 5x scattered-dword write amplification).

#define THREADS 512

typedef __attribute__((ext_vector_type(8))) short short8;
typedef __attribute__((ext_vector_type(4))) float f32x4;
typedef f32x4 __attribute__((aligned(4))) f32x4u;   // 4B-aligned vec store

__device__ __forceinline__ unsigned short f2bf(float x) {
    unsigned u = __float_as_uint(x);
    u += 0x7fffu + ((u >> 16) & 1u);   // round-to-nearest-even
    return (unsigned short)(u >> 16);
}
__device__ __forceinline__ float bf2f(unsigned short b) {
    return __uint_as_float(((unsigned)b) << 16);
}
__device__ __forceinline__ float sigm(float x) { return 1.0f / (1.0f + __expf(-x)); }

// ---------------------------------------------------------------------------
// Pack W_iou (384x256) -> Wl ; [U_iou (384x256); U_f (256x256)] -> Wc (640x256)
__global__ __launch_bounds__(256)
void prep_kernel(const float* __restrict__ W_iou,
                 const float* __restrict__ U_iou,
                 const float* __restrict__ U_f,
                 unsigned short* __restrict__ Wl,
                 unsigned short* __restrict__ Wc)
{
    const int i = blockIdx.x * 256 + threadIdx.x;   // grid covers 98304
    if (i < 98304) {
        Wl[i] = f2bf(W_iou[i]);
        Wc[i] = f2bf(U_iou[i]);
    }
    if (i < 65536) {
        Wc[98304 + i] = f2bf(U_f[i]);
    }
}

// ---------------------------------------------------------------------------
// One level's GEMM + LSTM epilogue.
// B-tile rows (512B, XOR-16B-chunk swizzled): row j = [h_prev[2j]|h_prev[2j+1]]
// (leaves: row i = emb[tok[i]]). Swapped MFMA: D[n][node]; wave w owns the
// p-slice [16w,16w+16); col groups n = p + j*128 keep i,o,u,f0,f1 in one lane.
// W loads are 2-deep double-buffered: per-j base address, ks*64 as load imm.
template<int NCOL, int G, bool WC>
__device__ __forceinline__ void level_step(
    const unsigned short* __restrict__ Wg,     // [NCOL*128][256] bf16, global
    const unsigned char* Blds,                 // B-tile base in LDS
    unsigned char* h_out,                      // LDS, B-tile format for next level
    unsigned short* c_out,                     // LDS, col-major [p][nslot_out]
    const unsigned short* c_prev, int nslot_prev,
    const float* __restrict__ b_iou, const float* __restrict__ b_f,
    int w, int lrow, int lk, int nslot_out, int mvalid)
{
    const int q0 = w * 16;
    // byte base for this lane's W fragment of col-group j at ks:
    //   Wg + (q0+lrow)*512 + j*65536 + lk*16 + ks*64
    const unsigned char* wbase = reinterpret_cast<const unsigned char*>(Wg)
                               + (q0 + lrow) * 512 + lk * 16;

    f32x4 acc[NCOL][G];
    #pragma unroll
    for (int j = 0; j < NCOL; ++j)
        #pragma unroll
        for (int g = 0; g < G; ++g)
            acc[j][g] = (f32x4){0.f, 0.f, 0.f, 0.f};

    short8 a0[NCOL], a1[NCOL];
    #pragma unroll
    for (int j = 0; j < NCOL; ++j)
        a0[j] = *reinterpret_cast<const short8*>(wbase + j * 65536);

    #pragma unroll
    for (int ks = 0; ks < 8; ++ks) {
        if (ks < 7) {                       // prefetch ks+1 into the other buf
            #pragma unroll
            for (int j = 0; j < NCOL; ++j) {
                short8 v = *reinterpret_cast<const short8*>(
                    wbase + j * 65536 + (ks + 1) * 64);
                if (ks & 1) a0[j] = v; else a1[j] = v;
            }
        }
        #pragma unroll
        for (int g = 0; g < G; ++g) {
            const int row = g * 16 + lrow;          // B-tile row = node slot
            const int chunk = (ks * 4 + lk) ^ (row & 7);
            short8 bN = *reinterpret_cast<const short8*>(
                Blds + row * 512 + (chunk << 4));
            #pragma unroll
            for (int j = 0; j < NCOL; ++j) {
                short8 a = (ks & 1) ? a1[j] : a0[j];   // static after unroll
                acc[j][g] = __builtin_amdgcn_mfma_f32_16x16x32_bf16(
                    a, bN, acc[j][g], 0, 0, 0);
            }
        }
    }

    #pragma unroll
    for (int g = 0; g < G; ++g) {
        const int ml = g * 16 + lrow;               // local node slot
        if (ml < mvalid) {
            #pragma unroll
            for (int r = 0; r < 4; ++r) {
                const int p = q0 + lk * 4 + r;
                float iv = acc[0][g][r] + b_iou[p];
                float ov = acc[1][g][r] + b_iou[128 + p];
                float uv = acc[2][g][r] + b_iou[256 + p];
                float csum = 0.f;
                if (NCOL == 5) {
                    float f0 = acc[3][g][r] + b_f[p];
                    float f1 = acc[4][g][r] + b_f[128 + p];
                    csum = sigm(f0) * bf2f(c_prev[p * nslot_prev + 2 * ml])
                         + sigm(f1) * bf2f(c_prev[p * nslot_prev + 2 * ml + 1]);
                }
                float cv = sigm(iv) * tanhf(uv) + csum;
                float hv = sigm(ov) * tanhf(cv);
                if (WC) c_out[p * nslot_out + ml] = f2bf(cv);
                const int jr = ml >> 1;
                const int q = (ml & 1) * 16 + (p >> 3);
                *reinterpret_cast<unsigned short*>(
                    h_out + jr * 512 + ((q ^ (jr & 7)) << 4) + (p & 7) * 2)
                    = f2bf(hv);
            }
        }
    }
}

// logits for M local nodes from swizzled LDS h; 4 lanes per node.
// Packed store: one 16B (align-4) vector + one dword => 2 scattered ops/node.
__device__ __forceinline__ void logits_emit(
    const unsigned char* h_lds, int M, const int* idsLds, int idBase,
    int segOff, const float* __restrict__ W_lin, const float* __restrict__ b_lin,
    float* __restrict__ out, int t)
{
    const int s = t >> 2, sub = t & 3;
    if (s >= M) return;
    float hv[32];
    const int j = s >> 1;
    #pragma unroll
    for (int qq = 0; qq < 4; ++qq) {
        const int q = (s & 1) * 16 + sub * 4 + qq;
        short8 v = *reinterpret_cast<const short8*>(
            h_lds + j * 512 + ((q ^ (j & 7)) << 4));
        #pragma unroll
        for (int e = 0; e < 8; ++e) hv[qq * 8 + e] = bf2f((unsigned short)v[e]);
    }
    const int gid = idsLds ? idsLds[s] : (idBase + s);
    float dots[5];
    #pragma unroll
    for (int cl = 0; cl < 5; ++cl) {
        const float* wr = W_lin + cl * 128 + sub * 32;
        float d = 0.f;
        #pragma unroll
        for (int k = 0; k < 32; ++k) d += hv[k] * wr[k];
        d += __shfl_xor(d, 1);
        d += __shfl_xor(d, 2);
        dots[cl] = d;
    }
    if (sub == 0) {
        float* op = out + (size_t)(segOff + gid) * 5;
        f32x4 v4 = { dots[0] + b_lin[0], dots[1] + b_lin[1],
                     dots[2] + b_lin[2], dots[3] + b_lin[3] };
        *reinterpret_cast<f32x4u*>(op) = v4;
        op[4] = dots[4] + b_lin[4];
    }
}

// ---------------------------------------------------------------------------
__global__ __launch_bounds__(THREADS, 4)   // 4 waves/EU -> 2 blocks/CU, VGPR<=128
void tree_kernel(const int*  __restrict__ leaf_x,
                 const int2* __restrict__ cpairs,   // l1:[0,131072) l2:+131072 l3:+196608
                 const float* __restrict__ emb,
                 const unsigned short* __restrict__ Wl,
                 const unsigned short* __restrict__ Wc,
                 const float* __restrict__ b_iou,
                 const float* __restrict__ b_f,
                 const float* __restrict__ W_lin,
                 const float* __restrict__ b_lin,
                 float* __restrict__ out)
{
    // Arena (65536 B), region-overlaid:
    //   A [0,32768):      X0 leaf B-tile (64 rows x 512B)
    //                     -> h1 [0,8192) + c1 [8192,16384) + h3 [16384,18432)
    //   B [32768,49152):  h0 (32 rows) -> h2 [32768,36864) + c2 [36864,40960)
    //   C [49152,65536):  c0 [p][64] bf16
    __shared__ unsigned char arena[65536];
    __shared__ int ids0[64], ids1[32], ids2[16], tok[64];

    const int t    = threadIdx.x;
    const int lane = t & 63;
    const int w    = t >> 6;       // wave = p-slice, 8 waves
    const int lrow = lane & 15;
    const int lk   = lane >> 4;
    const int blk3 = blockIdx.x * 8;   // 8 level-3 roots per block

    // ---- id chase: local slot s's children are local slots 2s,2s+1 ----
    if (t < 8)  { int2 p = cpairs[196608 + blk3 + t]; ids2[2*t] = p.x; ids2[2*t+1] = p.y; }
    __syncthreads();
    if (t < 16) { int2 p = cpairs[131072 + ids2[t]];  ids1[2*t] = p.x; ids1[2*t+1] = p.y; }
    __syncthreads();
    if (t < 32) { int2 p = cpairs[ids1[t]];           ids0[2*t] = p.x; ids0[2*t+1] = p.y; }
    __syncthreads();
    if (t < 64) { tok[t] = leaf_x[ids0[t]]; }
    __syncthreads();

    unsigned char*  X0 = arena;
    unsigned char*  h0 = arena + 32768;
    unsigned short* c0 = (unsigned short*)(arena + 49152);
    unsigned char*  h1 = arena;
    unsigned short* c1 = (unsigned short*)(arena + 8192);
    unsigned char*  h2 = arena + 32768;
    unsigned short* c2 = (unsigned short*)(arena + 36864);
    unsigned char*  h3 = arena + 16384;

    // ---- stage 64 leaf rows (emb f32 -> bf16, XOR-swizzled 16B chunks) ----
    {
        const int c  = t & 31;      // 16B chunk
        const int r0 = t >> 5;      // [0,16)
        #pragma unroll
        for (int rr = 0; rr < 4; ++rr) {
            const int r  = r0 + rr * 16;           // [0,64)
            const int gi = tok[r];
            const float4* src = reinterpret_cast<const float4*>(
                emb + (size_t)gi * 256 + c * 8);
            float4 a = src[0], b = src[1];
            short8 v;
            v[0]=(short)f2bf(a.x); v[1]=(short)f2bf(a.y);
            v[2]=(short)f2bf(a.z); v[3]=(short)f2bf(a.w);
            v[4]=(short)f2bf(b.x); v[5]=(short)f2bf(b.y);
            v[6]=(short)f2bf(b.z); v[7]=(short)f2bf(b.w);
            *reinterpret_cast<short8*>(X0 + r * 512 + ((c ^ (r & 7)) << 4)) = v;
        }
    }
    __syncthreads();

    // ---- leaves: 64 nodes, one step (G=4) ----
    level_step<3, 4, true>(Wl, X0, h0, c0, nullptr, 0, b_iou, b_f,
                           w, lrow, lk, 64, 64);
    __syncthreads();

    // ---- level 1: 32 nodes ----
    logits_emit(h0, 64, ids0, 0, 0, W_lin, b_lin, out, t);
    level_step<5, 2, true>(Wc, h0, h1, c1, c0, 64, b_iou, b_f,
                           w, lrow, lk, 32, 32);
    __syncthreads();

    // ---- level 2: 16 nodes ----
    logits_emit(h1, 32, ids1, 0, 262144, W_lin, b_lin, out, t);
    level_step<5, 1, true>(Wc, h1, h2, c2, c1, 32, b_iou, b_f,
                           w, lrow, lk, 16, 16);
    __syncthreads();

    // ---- level 3: 8 nodes (m-group padded to 16; stale columns discarded) ----
    logits_emit(h2, 16, ids2, 0, 393216, W_lin, b_lin, out, t);
    level_step<5, 1, false>(Wc, h2, h3, nullptr, c2, 16, b_iou, b_f,
                            w, lrow, lk, 8, 8);
    __syncthreads();

    logits_emit(h3, 8, nullptr, blk3, 458752, W_lin, b_lin, out, t);
}

// ---------------------------------------------------------------------------
extern "C" void kernel_launch(void* const* d_in, const int* in_sizes, int n_in,
                              void* d_out, int out_size, void* d_ws, size_t ws_size,
                              hipStream_t stream)
{
    const int*   leaf_x = (const int*)d_in[0];
    const int*   child  = (const int*)d_in[1];
    const float* emb    = (const float*)d_in[2];
    const float* W_iou  = (const float*)d_in[3];
    const float* U_iou  = (const float*)d_in[4];
    const float* b_iou  = (const float*)d_in[5];
    const float* U_f    = (const float*)d_in[6];
    const float* b_f    = (const float*)d_in[7];
    const float* W_lin  = (const float*)d_in[8];
    const float* b_lin  = (const float*)d_in[9];
    float* out = (float*)d_out;

    char* ws = (char*)d_ws;
    unsigned short* Wl = (unsigned short*)ws;                 // 192 KiB
    unsigned short* Wc = (unsigned short*)(ws + 196608);      // 320 KiB

    prep_kernel<<<384, 256, 0, stream>>>(W_iou, U_iou, U_f, Wl, Wc);

    tree_kernel<<<4096, THREADS, 0, stream>>>(
        leaf_x, (const int2*)child, emb, Wl, Wc,
        b_iou, b_f, W_lin, b_lin, out);
}